// Round 15
// baseline (213.518 us; speedup 1.0000x reference)
//
#include <hip/hip_runtime.h>

#define M_TOTAL 8192
#define KDIM 1024
#define TASKS 20
#define SBUF 256

typedef __attribute__((ext_vector_type(4))) int i32x4;
typedef __attribute__((ext_vector_type(8))) int i32x8;
typedef __attribute__((ext_vector_type(16))) float f32x16;

__device__ __forceinline__ void gload_lds16(const void* g, char* l) {
  __builtin_amdgcn_global_load_lds((const __attribute__((address_space(1))) void*)g,
                                   (__attribute__((address_space(3))) void*)l, 16, 0, 0);
}

#define FENCE() asm volatile("" ::: "memory")
#define BAR() do { FENCE(); __builtin_amdgcn_s_barrier(); FENCE(); } while (0)
#define LGKM0() asm volatile("s_waitcnt lgkmcnt(0)" ::: "memory")
#define VMC(n) asm volatile("s_waitcnt vmcnt(" #n ")" ::: "memory")
#define SCHED0() __builtin_amdgcn_sched_barrier(0)
// All scale bytes = 0x7F (E8M0 exp 0 -> x1.0): plain fp8 GEMM at MX rate.
#define MFMA_(a, bb, c) \
  (c) = __builtin_amdgcn_mfma_scale_f32_32x32x64_f8f6f4((a), (bb), (c), 0, 0, \
                                                        0, 0x7F7F7F7F, 0, 0x7F7F7F7F)

// One block per row: L2-normalize a 1024-float row of X or W, emit fp8 e4m3
// (RNE via v_cvt_pk_fp8_f32). First 640 blocks also init out[] to -1e30 for
// the atomicMin combine (runs before gemm in stream order).
__global__ __launch_bounds__(256) void norm_rows_kernel(const float* __restrict__ X,
                                                        const float* __restrict__ W,
                                                        unsigned int* __restrict__ Xq,
                                                        unsigned int* __restrict__ Wq,
                                                        float* __restrict__ out) {
  const int row = blockIdx.x;
  const int tid = threadIdx.x;
  if (row < (M_TOTAL * TASKS) / 256) out[row * 256 + tid] = -1e30f;
  const float* in;
  unsigned int* outp;
  int r;
  if (row < M_TOTAL) { in = X; outp = Xq; r = row; }
  else               { in = W; outp = Wq; r = row - M_TOTAL; }
  const float4 v = ((const float4*)(in + (size_t)r * KDIM))[tid];
  float s = v.x * v.x + v.y * v.y + v.z * v.z + v.w * v.w;
#pragma unroll
  for (int off = 32; off >= 1; off >>= 1) s += __shfl_xor(s, off, 64);
  __shared__ float part[4];
  if ((tid & 63) == 0) part[tid >> 6] = s;
  __syncthreads();
  s = part[0] + part[1] + part[2] + part[3];
  const float sc = rsqrtf(s);
  int pk = __builtin_amdgcn_cvt_pk_fp8_f32(v.x * sc, v.y * sc, 0, false);
  pk = __builtin_amdgcn_cvt_pk_fp8_f32(v.z * sc, v.w * sc, pk, true);
  outp[(size_t)r * (KDIM / 4) + tid] = (unsigned int)pk;
}

// 128(M) x 128(N) x BK=128 fp8-MX tile, 32x32x64 MFMA shape (layouts
// HW-verified in r13: absmax 0.0078). 256 thr = 4 waves (2M x 2N), wave tile
// 64x64 = 2x2 32x32 tiles, acc[2][2] f32x16 (64 AGPR).
// *** Register model (r3/r6/r7/r11/r13/r14-calibrated): under
// __launch_bounds__(256,2) the backend splits the 256-reg/wave budget evenly:
// accum_offset=128 -> arch cap 128, AGPR cap 128. acc (64) fits AGPR. r13
// spilled because BOTH k-steps' 8 LD32s were hoisted above the MFMAs (64 frag
// regs live + ~60 addressing > 128). Fix: sched_barrier(0) at each KSTEP end
// pins liveness to ONE k-step (32 frag regs) -> arch ~95 <= 128, no spill,
// 2 waves/SIMD, 2 blocks/CU (LDS 66.5 KB x2 = 133 KB <= 160 KB). ***
// Layouts: A row=lane&31, k=(lane>>5)*32+e; B col=lane&31 same k; C/D
// col=lane&31, row=(reg&3)+8*(reg>>2)+4*(lane>>5) (m74/m101).
// LDS per buf (32 KB at B_*32768): A [0,16K) 128-B rows, B [16K,32K).
// Swizzle: granule slot' = c16 ^ (row&7); k-step1 = step0 ^ 4 -> byte ^ 64.
// Stage dest linear, source inverse-permuted (rule #21). 8 K-tiles,
// 2-barrier KTILE, counted VMC(8) 2-deep ledger.
__global__ __launch_bounds__(256, 2) void gemm_min_kernel(const unsigned char* __restrict__ Xq,
                                                          const unsigned char* __restrict__ Wq,
                                                          float* __restrict__ out) {
  __shared__ __align__(16) char sm[66560];

  const int tid = threadIdx.x;
  const int lane = tid & 63;
  const int w = tid >> 6, wr = w >> 1, wc = w & 1;
  const int l31 = lane & 31, l2 = lane >> 5;

  // XCD swizzle: 2560 blocks; xcd owns an 8-mblk stripe, mblk fastest, nblk slow.
  const int o = blockIdx.x;
  const int xcd = o & 7, i = o >> 3;        // i in [0,320)
  const int nblk = i >> 3;                   // 0..39
  const int mblk = xcd * 8 + (i & 7);        // 0..63
  const int rowBase = mblk * 128;
  const int col0 = nblk * 128;
  const int task = nblk >> 1;

  // staging source decode (inverse of slot' = c16 ^ (row&7)); chunk ii adds
  // 32 rows (ii*32*KDIM source, ii*4096 linear dest) — c16 chunk-invariant.
  const int c16 = (tid & 7) ^ ((tid >> 3) & 7);
  const unsigned char* pA = Xq + (size_t)(rowBase + (tid >> 3)) * KDIM + c16 * 16;
  const unsigned char* pB = Wq + (size_t)(col0 + (tid >> 3)) * KDIM + c16 * 16;

  // frag read bases: row = (wr|wc)*64 + mi*32 + l31 (row&7 = lane&7);
  // k-step0 granules l2*2, l2*2+1 -> phys (l2*2)^(lane&7), ^1 via off^16;
  // k-step1: ^4 via off^64.
  const int slot = ((l2 * 2) ^ (lane & 7)) * 16;
  const int aBase = (wr * 64 + l31) * 128 + slot;
  const int bBase = 16384 + (wc * 64 + l31) * 128 + slot;

  f32x16 acc[2][2] = {};

  // 8 loads/thread/K-tile into buf B_: A chunks 0..3 (128 rows), B chunks 0..3
#define STG(B_, kB) do { \
    _Pragma("unroll") for (int ii = 0; ii < 4; ++ii) { \
      gload_lds16(pA + (size_t)ii * 32 * KDIM + (kB), sm + (B_) * 32768 + ii * 4096 + tid * 16); \
      gload_lds16(pB + (size_t)ii * 32 * KDIM + (kB), sm + (B_) * 32768 + 16384 + ii * 4096 + tid * 16); \
    } } while (0)

  // well-defined 32-byte fragment load: two i32x4 LDS reads + shufflevector
#define LD32(dst, base_, off_) do { \
    i32x4 lo_ = *(const i32x4*)((base_) + (off_)); \
    i32x4 hi_ = *(const i32x4*)((base_) + ((off_) ^ 16)); \
    (dst) = __builtin_shufflevector(lo_, hi_, 0, 1, 2, 3, 4, 5, 6, 7); \
  } while (0)

  // prologue: tile0 -> buf0, tile1 -> buf1; VMC(8) -> tile0 resident
  STG(0, 0);
  STG(1, 128);
  VMC(8); SCHED0();
  BAR();

  // Per K-tile: {ks0: 4 frag loads + 4 MFMA; SCHED0 fence (liveness cap);
  //  ks1 (off^64): same; LGKM0; BAR; STG t+2 -> own buf; VMC(8); BAR}.
#define KSTEP(base, xorv) do { \
    i32x8 aF[2], bF[2]; \
    LD32(aF[0], base, (aBase) ^ (xorv)); \
    LD32(aF[1], base, (aBase + 4096) ^ (xorv)); \
    LD32(bF[0], base, (bBase) ^ (xorv)); \
    LD32(bF[1], base, (bBase + 4096) ^ (xorv)); \
    __builtin_amdgcn_s_setprio(1); \
    MFMA_(aF[0], bF[0], acc[0][0]); MFMA_(aF[0], bF[1], acc[0][1]); \
    MFMA_(aF[1], bF[0], acc[1][0]); MFMA_(aF[1], bF[1], acc[1][1]); \
    __builtin_amdgcn_s_setprio(0); \
    SCHED0(); \
  } while (0)

#define KTILE(B_, kt) do { \
    const char* base = sm + (B_) * 32768; \
    KSTEP(base, 0); \
    KSTEP(base, 64); \
    LGKM0(); SCHED0(); \
    BAR(); \
    { const int kB = ((kt) + 2 < 8) ? ((kt) + 2) * 128 : 0; STG(B_, kB); } \
    VMC(8); SCHED0(); \
    BAR(); \
  } while (0)

  for (int kt = 0; kt < 8; kt += 2) {
    KTILE(0, kt);
    KTILE(1, kt + 1);
  }

  // Drain wrap-garbage stages before reusing LDS / ending the block (r5 race).
  VMC(0); SCHED0();
  BAR();

  // epilogue: per-row max-dot over 2 n-tiles + 32 col-lanes -> red -> atomic.
  float (*red)[2] = (float (*)[2])(sm + 65536);  // outside staging regions
#pragma unroll
  for (int mi = 0; mi < 2; ++mi) {
#pragma unroll
    for (int r = 0; r < 16; ++r) {
      float v = fmaxf(acc[mi][0][r], acc[mi][1][r]);
      v = fmaxf(v, __shfl_xor(v, 1, 64));
      v = fmaxf(v, __shfl_xor(v, 2, 64));
      v = fmaxf(v, __shfl_xor(v, 4, 64));
      v = fmaxf(v, __shfl_xor(v, 8, 64));
      v = fmaxf(v, __shfl_xor(v, 16, 64));
      if (l31 == 0)
        red[wr * 64 + mi * 32 + (r & 3) + 8 * (r >> 2) + 4 * l2][wc] = v;
    }
  }
  BAR();
  if (tid < 128) {
    const float vv = fmaxf(red[tid][0], red[tid][1]);
    const float d = sqrtf(fmaxf(2.0f - 2.0f * vv, 1e-12f));
    // all published values negative: uint atomicMin == float max == -min dist
    atomicMin((unsigned int*)&out[(size_t)(rowBase + tid) * TASKS + task],
              __float_as_uint(-d));
  }
#undef KTILE
#undef KSTEP
#undef LD32
#undef STG
}

extern "C" void kernel_launch(void* const* d_in, const int* in_sizes, int n_in,
                              void* d_out, int out_size, void* d_ws, size_t ws_size,
                              hipStream_t stream) {
  const float* X = (const float*)d_in[0];   // (8192, 1024) fp32
  const float* W = (const float*)d_in[1];   // (5120, 1024) fp32
  float* out = (float*)d_out;               // (8192, 20) fp32

  unsigned char* Xq = (unsigned char*)d_ws;                          // 8.4 MB fp8
  unsigned char* Wq = Xq + (size_t)M_TOTAL * KDIM;                   // 5.2 MB fp8

  norm_rows_kernel<<<M_TOTAL + TASKS * SBUF, 256, 0, stream>>>(
      X, W, (unsigned int*)Xq, (unsigned int*)Wq, out);
  gemm_min_kernel<<<2560, 256, 0, stream>>>(Xq, Wq, out);
}

// Round 16
// 101.780 us; speedup vs baseline: 2.0978x; 2.0978x over previous
//
#include <hip/hip_runtime.h>

#define M_TOTAL 8192
#define KDIM 1024
#define TASKS 20
#define SBUF 256

typedef __attribute__((ext_vector_type(8))) int i32x8;
typedef __attribute__((ext_vector_type(16))) float f32x16;

__device__ __forceinline__ void gload_lds16(const void* g, char* l) {
  __builtin_amdgcn_global_load_lds((const __attribute__((address_space(1))) void*)g,
                                   (__attribute__((address_space(3))) void*)l, 16, 0, 0);
}

#define FENCE() asm volatile("" ::: "memory")
#define BAR() do { FENCE(); __builtin_amdgcn_s_barrier(); FENCE(); } while (0)
#define LGKM0() asm volatile("s_waitcnt lgkmcnt(0)" ::: "memory")
#define VMC(n) asm volatile("s_waitcnt vmcnt(" #n ")" ::: "memory")
#define SCHED0() __builtin_amdgcn_sched_barrier(0)
// All scale bytes = 0x7F (E8M0 exp 0 -> x1.0): plain fp8 GEMM at MX rate.
#define MFMA_(a, bb, c) \
  (c) = __builtin_amdgcn_mfma_scale_f32_32x32x64_f8f6f4((a), (bb), (c), 0, 0, \
                                                        0, 0x7F7F7F7F, 0, 0x7F7F7F7F)

// One block per row: L2-normalize a 1024-float row of X or W, emit fp8 e4m3
// (RNE via v_cvt_pk_fp8_f32). First 640 blocks also init out[] to -1e30 for
// the atomicMin combine (runs before gemm in stream order).
__global__ __launch_bounds__(256) void norm_rows_kernel(const float* __restrict__ X,
                                                        const float* __restrict__ W,
                                                        unsigned int* __restrict__ Xq,
                                                        unsigned int* __restrict__ Wq,
                                                        float* __restrict__ out) {
  const int row = blockIdx.x;
  const int tid = threadIdx.x;
  if (row < (M_TOTAL * TASKS) / 256) out[row * 256 + tid] = -1e30f;
  const float* in;
  unsigned int* outp;
  int r;
  if (row < M_TOTAL) { in = X; outp = Xq; r = row; }
  else               { in = W; outp = Wq; r = row - M_TOTAL; }
  const float4 v = ((const float4*)(in + (size_t)r * KDIM))[tid];
  float s = v.x * v.x + v.y * v.y + v.z * v.z + v.w * v.w;
#pragma unroll
  for (int off = 32; off >= 1; off >>= 1) s += __shfl_xor(s, off, 64);
  __shared__ float part[4];
  if ((tid & 63) == 0) part[tid >> 6] = s;
  __syncthreads();
  s = part[0] + part[1] + part[2] + part[3];
  const float sc = rsqrtf(s);
  int pk = __builtin_amdgcn_cvt_pk_fp8_f32(v.x * sc, v.y * sc, 0, false);
  pk = __builtin_amdgcn_cvt_pk_fp8_f32(v.z * sc, v.w * sc, pk, true);
  outp[(size_t)r * (KDIM / 4) + tid] = (unsigned int)pk;
}

// 128(M) x 128(N) x BK=128 fp8-MX tile, 32x32x64 shape (layouts HW-verified
// r13: absmax 0.0078). 256 thr = 4 waves (2M x 2N), wave tile 64x64 = 2x2
// 32x32, acc[2][2] f32x16.
// *** LEAN-REGISTER rewrite (r11-r15 lesson: the knot is arch-VGPR demand).
// 32-B-granule swizzle: row r (4x 32B granules) stores granule g at
// g' = g ^ (r&3). A lane's 32-B fragment (k = l2*32+e within the ks*64
// window) is granule ks*2+l2 -> ONE contiguous i32x8 load (2 ds_read_b128,
// 1 base + imm) instead of 2 scattered 16B loads + shufflevector. All of
// {buffer, region, mi} are 16-bit ds imm offsets -> 4 LDS base VGPRs total.
// Conflict-free: 8 lanes/bank uniform (the 4-clk wave64 floor).
// #pragma unroll 1 on the K-loop stops the 8-tile address balloon (r14's
// 232 arch). Demand ~90-110 arch + 64 acc -> ~170/wave -> 2 blocks/CU at
// (256,1) even if acc stays in the arch file (2x170 <= 512 pool; LDS 66.5KB
// allows 2). If VGPR_Count still >256 -> fp8 path abandoned, revert r9. ***
// Stage: thread t covers 16B at linear dest ii*4096 + t*16; source row
// t>>3 (+32*ii), logical granule ((t>>1)&3) ^ ((t>>3)&3), half t&1 (rule #21).
// 8 K-tiles, 2-barrier KTILE, counted VMC(8) 2-deep ledger.
// Half-task columns combined via uint atomicMin of negative floats (exact).
__global__ __launch_bounds__(256, 1) void gemm_min_kernel(const unsigned char* __restrict__ Xq,
                                                          const unsigned char* __restrict__ Wq,
                                                          float* __restrict__ out) {
  __shared__ __align__(32) char sm[66560];

  const int tid = threadIdx.x;
  const int lane = tid & 63;
  const int w = tid >> 6, wr = w >> 1, wc = w & 1;
  const int l31 = lane & 31, l2 = lane >> 5;

  // XCD swizzle: 2560 blocks; xcd owns an 8-mblk stripe, mblk fastest, nblk slow.
  const int o = blockIdx.x;
  const int xcd = o & 7, i = o >> 3;        // i in [0,320)
  const int nblk = i >> 3;                   // 0..39
  const int mblk = xcd * 8 + (i & 7);        // 0..63
  const int rowBase = mblk * 128;
  const int col0 = nblk * 128;
  const int task = nblk >> 1;

  // staging source (inverse 32B-granule swizzle)
  const int srow = tid >> 3;
  const int soff = ((((tid >> 1) & 3) ^ ((tid >> 3) & 3)) * 32) + (tid & 1) * 16;
  const unsigned char* pA = Xq + (size_t)(rowBase + srow) * KDIM + soff;
  const unsigned char* pB = Wq + (size_t)(col0 + srow) * KDIM + soff;

  // LDS read bases: 4 VGPRs; {buf, region, mi} via immediates.
  // granule(ks) = ks*2 + l2; phys = granule ^ (l31&3); byte = row*128 + phys*32.
  const char* aks0 = sm + (wr * 64 + l31) * 128 + ((l2) ^ (l31 & 3)) * 32;
  const char* aks1 = sm + (wr * 64 + l31) * 128 + ((2 + l2) ^ (l31 & 3)) * 32;
  const char* bks0 = sm + 16384 + (wc * 64 + l31) * 128 + ((l2) ^ (l31 & 3)) * 32;
  const char* bks1 = sm + 16384 + (wc * 64 + l31) * 128 + ((2 + l2) ^ (l31 & 3)) * 32;

  f32x16 acc[2][2] = {};

  // 8 loads/thread/K-tile into buf B_: A chunks 0..3 (128 rows), B chunks 0..3
#define STG(B_, kB) do { \
    _Pragma("unroll") for (int ii = 0; ii < 4; ++ii) { \
      gload_lds16(pA + (size_t)ii * 32 * KDIM + (kB), sm + (B_) * 32768 + ii * 4096 + tid * 16); \
      gload_lds16(pB + (size_t)ii * 32 * KDIM + (kB), sm + (B_) * 32768 + 16384 + ii * 4096 + tid * 16); \
    } } while (0)

#define KSTEP(B_, ak, bk) do { \
    i32x8 aF0 = *(const i32x8*)((ak) + (B_) * 32768); \
    i32x8 aF1 = *(const i32x8*)((ak) + (B_) * 32768 + 4096); \
    i32x8 bF0 = *(const i32x8*)((bk) + (B_) * 32768); \
    i32x8 bF1 = *(const i32x8*)((bk) + (B_) * 32768 + 4096); \
    __builtin_amdgcn_s_setprio(1); \
    MFMA_(aF0, bF0, acc[0][0]); MFMA_(aF0, bF1, acc[0][1]); \
    MFMA_(aF1, bF0, acc[1][0]); MFMA_(aF1, bF1, acc[1][1]); \
    __builtin_amdgcn_s_setprio(0); \
  } while (0)

  // Per K-tile: {ks0 + ks1 (4 frag loads + 4 MFMA each); LGKM0; BAR;
  //              STG t+2 -> own buf; VMC(8) [t+1 resident]; BAR}.
#define KTILE(B_, kB2) do { \
    KSTEP(B_, aks0, bks0); \
    KSTEP(B_, aks1, bks1); \
    LGKM0(); SCHED0(); \
    BAR(); \
    STG(B_, kB2); \
    VMC(8); SCHED0(); \
    BAR(); \
  } while (0)

  // prologue: tile0 -> buf0, tile1 -> buf1; VMC(8) -> tile0 resident
  STG(0, 0);
  STG(1, 128);
  VMC(8); SCHED0();
  BAR();

#pragma unroll 1
  for (int kt = 0; kt < 8; kt += 2) {
    const int k2 = (kt + 2 < 8) ? (kt + 2) * 128 : 0;   // bytes (fp8): tile k-offset
    const int k3 = (kt + 3 < 8) ? (kt + 3) * 128 : 0;
    KTILE(0, k2);
    KTILE(1, k3);
  }

  // Drain wrap-garbage stages before reusing LDS / ending the block (r5 race).
  VMC(0); SCHED0();
  BAR();

  // epilogue: per-row max-dot over 2 n-tiles + 32 col-lanes -> red -> atomic.
  // C/D layout (r13 HW-verified): col=lane&31, row=(reg&3)+8*(reg>>2)+4*l2.
  float (*red)[2] = (float (*)[2])(sm + 65536);  // outside staging regions
#pragma unroll
  for (int mi = 0; mi < 2; ++mi) {
#pragma unroll
    for (int r = 0; r < 16; ++r) {
      float v = fmaxf(acc[mi][0][r], acc[mi][1][r]);
      v = fmaxf(v, __shfl_xor(v, 1, 64));
      v = fmaxf(v, __shfl_xor(v, 2, 64));
      v = fmaxf(v, __shfl_xor(v, 4, 64));
      v = fmaxf(v, __shfl_xor(v, 8, 64));
      v = fmaxf(v, __shfl_xor(v, 16, 64));
      if (l31 == 0)
        red[wr * 64 + mi * 32 + (r & 3) + 8 * (r >> 2) + 4 * l2][wc] = v;
    }
  }
  BAR();
  if (tid < 128) {
    const float vv = fmaxf(red[tid][0], red[tid][1]);
    const float d = sqrtf(fmaxf(2.0f - 2.0f * vv, 1e-12f));
    // all published values negative: uint atomicMin == float max == -min dist
    atomicMin((unsigned int*)&out[(size_t)(rowBase + tid) * TASKS + task],
              __float_as_uint(-d));
  }
#undef KTILE
#undef KSTEP
#undef STG
}

extern "C" void kernel_launch(void* const* d_in, const int* in_sizes, int n_in,
                              void* d_out, int out_size, void* d_ws, size_t ws_size,
                              hipStream_t stream) {
  const float* X = (const float*)d_in[0];   // (8192, 1024) fp32
  const float* W = (const float*)d_in[1];   // (5120, 1024) fp32
  float* out = (float*)d_out;               // (8192, 20) fp32

  unsigned char* Xq = (unsigned char*)d_ws;                          // 8.4 MB fp8
  unsigned char* Wq = Xq + (size_t)M_TOTAL * KDIM;                   // 5.2 MB fp8

  norm_rows_kernel<<<M_TOTAL + TASKS * SBUF, 256, 0, stream>>>(
      X, W, (unsigned int*)Xq, (unsigned int*)Wq, out);
  gemm_min_kernel<<<2560, 256, 0, stream>>>(Xq, Wq, out);
}

// Round 17
// 95.809 us; speedup vs baseline: 2.2286x; 1.0623x over previous
//
#include <hip/hip_runtime.h>

#define M_TOTAL 8192
#define KDIM 1024
#define TASKS 20
#define SBUF 256

typedef __attribute__((ext_vector_type(4))) int i32x4;
typedef __attribute__((ext_vector_type(8))) int i32x8;
typedef __attribute__((ext_vector_type(16))) float f32x16;

__device__ __forceinline__ void gload_lds16(const void* g, char* l) {
  __builtin_amdgcn_global_load_lds((const __attribute__((address_space(1))) void*)g,
                                   (__attribute__((address_space(3))) void*)l, 16, 0, 0);
}

#define FENCE() asm volatile("" ::: "memory")
#define BAR() do { FENCE(); __builtin_amdgcn_s_barrier(); FENCE(); } while (0)
#define LGKM0() asm volatile("s_waitcnt lgkmcnt(0)" ::: "memory")
#define VMC(n) asm volatile("s_waitcnt vmcnt(" #n ")" ::: "memory")
#define SCHED0() __builtin_amdgcn_sched_barrier(0)
// All scale bytes = 0x7F (E8M0 exp 0 -> x1.0): plain fp8 GEMM at MX rate.
#define MFMA_(a, bb, c) \
  (c) = __builtin_amdgcn_mfma_scale_f32_32x32x64_f8f6f4((a), (bb), (c), 0, 0, \
                                                        0, 0x7F7F7F7F, 0, 0x7F7F7F7F)

// One block per row: L2-normalize a 1024-float row of X or W, emit fp8 e4m3
// (RNE via v_cvt_pk_fp8_f32). First 640 blocks also init out[] to -1e30 for
// the atomicMin combine (runs before gemm in stream order).
__global__ __launch_bounds__(256) void norm_rows_kernel(const float* __restrict__ X,
                                                        const float* __restrict__ W,
                                                        unsigned int* __restrict__ Xq,
                                                        unsigned int* __restrict__ Wq,
                                                        float* __restrict__ out) {
  const int row = blockIdx.x;
  const int tid = threadIdx.x;
  if (row < (M_TOTAL * TASKS) / 256) out[row * 256 + tid] = -1e30f;
  const float* in;
  unsigned int* outp;
  int r;
  if (row < M_TOTAL) { in = X; outp = Xq; r = row; }
  else               { in = W; outp = Wq; r = row - M_TOTAL; }
  const float4 v = ((const float4*)(in + (size_t)r * KDIM))[tid];
  float s = v.x * v.x + v.y * v.y + v.z * v.z + v.w * v.w;
#pragma unroll
  for (int off = 32; off >= 1; off >>= 1) s += __shfl_xor(s, off, 64);
  __shared__ float part[4];
  if ((tid & 63) == 0) part[tid >> 6] = s;
  __syncthreads();
  s = part[0] + part[1] + part[2] + part[3];
  const float sc = rsqrtf(s);
  int pk = __builtin_amdgcn_cvt_pk_fp8_f32(v.x * sc, v.y * sc, 0, false);
  pk = __builtin_amdgcn_cvt_pk_fp8_f32(v.z * sc, v.w * sc, pk, true);
  outp[(size_t)r * (KDIM / 4) + tid] = (unsigned int)pk;
}

// 128(M) x 128(N) x BK=128 fp8-MX tile, 32x32x64 shape (layouts HW-verified
// r13: absmax 0.0078). 256 thr = 4 waves (2M x 2N), wave tile 64x64 = 2x2
// 32x32, acc[2][2] f32x16. r16 lean-register skeleton ((256,1), imm-offset
// addressing, #pragma unroll 1 K-loop) = 104 arch regs, 2 blocks/CU.
// *** r16 fix: bank swizzle back to 16-B granules (r13's). r16's 32-B
// granules folded (l2, l31&3) onto 4 granule values via XOR -> 16 lanes on
// one 4-bank group per b128 (6144 conflict cyc/block, 3x r13). 16-B slots:
// phys = (ks*4 + l2*2 + h) ^ (l31&7) -> 8 slots, 2 lanes/slot (2-way = free,
// m136). Fragment = two b128 at slot and slot^1, combined by shufflevector
// (no typed stores - r10 TBAA lesson). 8 LDS base VGPRs (lo/hi x A/B x ks). ***
// LDS per buf (32 KB at B_*32768): A [0,16K) 128-B rows, B [16K,32K).
// Stage: thread t -> linear dest ii*4096 + t*16; source slot
// ((t&7) ^ ((t>>3)&7))*16 is the inverse permutation (rule #21, r13-proven).
// 8 K-tiles, 2-barrier KTILE, counted VMC(8) 2-deep ledger.
// Half-task columns combined via uint atomicMin of negative floats (exact).
__global__ __launch_bounds__(256, 1) void gemm_min_kernel(const unsigned char* __restrict__ Xq,
                                                          const unsigned char* __restrict__ Wq,
                                                          float* __restrict__ out) {
  __shared__ __align__(32) char sm[66560];

  const int tid = threadIdx.x;
  const int lane = tid & 63;
  const int w = tid >> 6, wr = w >> 1, wc = w & 1;
  const int l31 = lane & 31, l2 = lane >> 5;
  const int l7 = l31 & 7;

  // XCD swizzle: 2560 blocks; xcd owns an 8-mblk stripe, mblk fastest, nblk slow.
  const int o = blockIdx.x;
  const int xcd = o & 7, i = o >> 3;        // i in [0,320)
  const int nblk = i >> 3;                   // 0..39
  const int mblk = xcd * 8 + (i & 7);        // 0..63
  const int rowBase = mblk * 128;
  const int col0 = nblk * 128;
  const int task = nblk >> 1;

  // staging source (inverse 16-B-slot swizzle, r13-proven)
  const int srow = tid >> 3;
  const int soff = ((tid & 7) ^ ((tid >> 3) & 7)) * 16;
  const unsigned char* pA = Xq + (size_t)(rowBase + srow) * KDIM + soff;
  const unsigned char* pB = Wq + (size_t)(col0 + srow) * KDIM + soff;

  // LDS read bases (8 VGPRs): per region x ks, lo/hi 16-B halves.
  // row = region + mi*32 + l31 (row&7 = l31&7); {buf, mi} via immediates.
  const int rowA = (wr * 64 + l31) * 128;
  const int rowB = 16384 + (wc * 64 + l31) * 128;
  const char* aL0 = sm + rowA + (((l2 * 2) ^ l7) * 16);
  const char* aH0 = sm + rowA + (((l2 * 2 + 1) ^ l7) * 16);
  const char* aL1 = sm + rowA + (((4 + l2 * 2) ^ l7) * 16);
  const char* aH1 = sm + rowA + (((4 + l2 * 2 + 1) ^ l7) * 16);
  const char* bL0 = sm + rowB + (((l2 * 2) ^ l7) * 16);
  const char* bH0 = sm + rowB + (((l2 * 2 + 1) ^ l7) * 16);
  const char* bL1 = sm + rowB + (((4 + l2 * 2) ^ l7) * 16);
  const char* bH1 = sm + rowB + (((4 + l2 * 2 + 1) ^ l7) * 16);

  f32x16 acc[2][2] = {};

  // 8 loads/thread/K-tile into buf B_: A chunks 0..3 (128 rows), B chunks 0..3
#define STG(B_, kB) do { \
    _Pragma("unroll") for (int ii = 0; ii < 4; ++ii) { \
      gload_lds16(pA + (size_t)ii * 32 * KDIM + (kB), sm + (B_) * 32768 + ii * 4096 + tid * 16); \
      gload_lds16(pB + (size_t)ii * 32 * KDIM + (kB), sm + (B_) * 32768 + 16384 + ii * 4096 + tid * 16); \
    } } while (0)

  // 32-B fragment: two b128 at swizzled slots, shufflevector combine (no UB)
#define LD32(dst, lo, hi, off_) do { \
    i32x4 lo_ = *(const i32x4*)((lo) + (off_)); \
    i32x4 hi_ = *(const i32x4*)((hi) + (off_)); \
    (dst) = __builtin_shufflevector(lo_, hi_, 0, 1, 2, 3, 4, 5, 6, 7); \
  } while (0)

#define KSTEP(B_, aL, aH, bL, bH) do { \
    i32x8 aF0, aF1, bF0, bF1; \
    LD32(aF0, aL, aH, (B_) * 32768); \
    LD32(aF1, aL, aH, (B_) * 32768 + 4096); \
    LD32(bF0, bL, bH, (B_) * 32768); \
    LD32(bF1, bL, bH, (B_) * 32768 + 4096); \
    __builtin_amdgcn_s_setprio(1); \
    MFMA_(aF0, bF0, acc[0][0]); MFMA_(aF0, bF1, acc[0][1]); \
    MFMA_(aF1, bF0, acc[1][0]); MFMA_(aF1, bF1, acc[1][1]); \
    __builtin_amdgcn_s_setprio(0); \
  } while (0)

  // Per K-tile: {ks0 + ks1 (4 frag loads + 4 MFMA each); LGKM0; BAR;
  //              STG t+2 -> own buf; VMC(8) [t+1 resident]; BAR}.
#define KTILE(B_, kB2) do { \
    KSTEP(B_, aL0, aH0, bL0, bH0); \
    KSTEP(B_, aL1, aH1, bL1, bH1); \
    LGKM0(); SCHED0(); \
    BAR(); \
    STG(B_, kB2); \
    VMC(8); SCHED0(); \
    BAR(); \
  } while (0)

  // prologue: tile0 -> buf0, tile1 -> buf1; VMC(8) -> tile0 resident
  STG(0, 0);
  STG(1, 128);
  VMC(8); SCHED0();
  BAR();

#pragma unroll 1
  for (int kt = 0; kt < 8; kt += 2) {
    const int k2 = (kt + 2 < 8) ? (kt + 2) * 128 : 0;   // bytes (fp8)
    const int k3 = (kt + 3 < 8) ? (kt + 3) * 128 : 0;
    KTILE(0, k2);
    KTILE(1, k3);
  }

  // Drain wrap-garbage stages before reusing LDS / ending the block (r5 race).
  VMC(0); SCHED0();
  BAR();

  // epilogue: per-row max-dot over 2 n-tiles + 32 col-lanes -> red -> atomic.
  // C/D layout (r13 HW-verified): col=lane&31, row=(reg&3)+8*(reg>>2)+4*l2.
  float (*red)[2] = (float (*)[2])(sm + 65536);  // outside staging regions
#pragma unroll
  for (int mi = 0; mi < 2; ++mi) {
#pragma unroll
    for (int r = 0; r < 16; ++r) {
      float v = fmaxf(acc[mi][0][r], acc[mi][1][r]);
      v = fmaxf(v, __shfl_xor(v, 1, 64));
      v = fmaxf(v, __shfl_xor(v, 2, 64));
      v = fmaxf(v, __shfl_xor(v, 4, 64));
      v = fmaxf(v, __shfl_xor(v, 8, 64));
      v = fmaxf(v, __shfl_xor(v, 16, 64));
      if (l31 == 0)
        red[wr * 64 + mi * 32 + (r & 3) + 8 * (r >> 2) + 4 * l2][wc] = v;
    }
  }
  BAR();
  if (tid < 128) {
    const float vv = fmaxf(red[tid][0], red[tid][1]);
    const float d = sqrtf(fmaxf(2.0f - 2.0f * vv, 1e-12f));
    // all published values negative: uint atomicMin == float max == -min dist
    atomicMin((unsigned int*)&out[(size_t)(rowBase + tid) * TASKS + task],
              __float_as_uint(-d));
  }
#undef KTILE
#undef KSTEP
#undef LD32
#undef STG
}

extern "C" void kernel_launch(void* const* d_in, const int* in_sizes, int n_in,
                              void* d_out, int out_size, void* d_ws, size_t ws_size,
                              hipStream_t stream) {
  const float* X = (const float*)d_in[0];   // (8192, 1024) fp32
  const float* W = (const float*)d_in[1];   // (5120, 1024) fp32
  float* out = (float*)d_out;               // (8192, 20) fp32

  unsigned char* Xq = (unsigned char*)d_ws;                          // 8.4 MB fp8
  unsigned char* Wq = Xq + (size_t)M_TOTAL * KDIM;                   // 5.2 MB fp8

  norm_rows_kernel<<<M_TOTAL + TASKS * SBUF, 256, 0, stream>>>(
      X, W, (unsigned int*)Xq, (unsigned int*)Wq, out);
  gemm_min_kernel<<<2560, 256, 0, stream>>>(Xq, Wq, out);
}